// Round 7
// baseline (471.480 us; speedup 1.0000x reference)
//
#include <hip/hip_runtime.h>
#include <hip/hip_cooperative_groups.h>
#include <math.h>

namespace cg = cooperative_groups;

// x [B=512, C=1024, H=8, W=8] f32. out same shape.
#define C_DIM 1024
#define HW 64
#define F4B 16384           // C_DIM*HW/4 float4 per batch
#define EPSV 1e-8f
#define TINYF 1.17549435e-38f

typedef float f32x4_t __attribute__((ext_vector_type(4)));

__device__ __forceinline__ void threefry2x32_01(unsigned x0, unsigned x1,
                                                unsigned& o0, unsigned& o1) {
    const unsigned ks0 = 0u, ks1 = 1u, ks2 = 0x1BD11BDBu; // 0x1BD11BDA ^ 0 ^ 1
    x0 += ks0; x1 += ks1;
#define TF_R(r) { x0 += x1; x1 = (x1 << (r)) | (x1 >> (32 - (r))); x1 ^= x0; }
    TF_R(13) TF_R(15) TF_R(26) TF_R(6)
    x0 += ks1; x1 += ks2 + 1u;
    TF_R(17) TF_R(29) TF_R(16) TF_R(24)
    x0 += ks2; x1 += ks0 + 2u;
    TF_R(13) TF_R(15) TF_R(26) TF_R(6)
    x0 += ks0; x1 += ks1 + 3u;
    TF_R(17) TF_R(29) TF_R(16) TF_R(24)
    x0 += ks1; x1 += ks2 + 4u;
    TF_R(13) TF_R(15) TF_R(26) TF_R(6)
    x0 += ks2; x1 += ks0 + 5u;
#undef TF_R
    o0 = x0; o1 = x1;
}

// jax_threefry_partitionable=True: counter (hi=0, lo=n), out = o0 ^ o1.
__device__ __forceinline__ unsigned jax_random_bits(unsigned n) {
    unsigned o0, o1;
    threefry2x32_01(0u, n, o0, o1);
    return o0 ^ o1;
}

__device__ __forceinline__ float gumbel01(unsigned n) {
    unsigned bits = jax_random_bits(n);
    float f = __uint_as_float(0x3F800000u | (bits >> 9)) - 1.0f;
    float u = fmaxf(TINYF, f + TINYF);
    return -logf(-logf(u));
}

__device__ __forceinline__ bool bad_val(float v) {
    return ((__float_as_uint(v) & 0x7F800000u) == 0x7F800000u) || (v < 0.0f);
}

// --------------- Single cooperative kernel, three grid-synced phases --------
// Grid = B*2 blocks x 256 threads (4 blocks/CU, co-resident).
// P1: each block stream-maxes 2 quarter-batches -> part[qb][64] in ws.
// P2: blocks 0..B-1, wave 0: middle network -> gate[b][64] in ws (parallel).
// P3: each block applies its 2 quarter-batches; x re-read hits L2/LLC;
//     nt stores keep out from evicting x.
__global__ __launch_bounds__(256, 4) void sa_coop_kernel(
    const float* __restrict__ x,
    const float* __restrict__ w11,
    const float* __restrict__ w5,
    const float* __restrict__ b5,
    const float* __restrict__ w6,
    const float* __restrict__ b6,
    float* __restrict__ out,
    float* __restrict__ part,
    float* __restrict__ gate,
    int B)
{
    cg::grid_group grid = cg::this_grid();
    const int bid = blockIdx.x;
    const int t = threadIdx.x;
    const int nblk = gridDim.x;          // B*2
    const float4* __restrict__ x4 = (const float4*)x;
    float4* __restrict__ o4 = (float4*)out;

    __shared__ float4 red[2][4 * 16];
    __shared__ float sm[64], sa16[16], sb16[16], so2[64], shid[4 * 64];

    // ---- Phase 1: partial channel max over 2 quarter-batches ----
#pragma unroll
    for (int r = 0; r < 2; ++r) {
        const int qb = bid + r * nblk;   // quarter-batch id
        const size_t base = (size_t)qb * 4096;
        float4 pm = make_float4(-INFINITY, -INFINITY, -INFINITY, -INFINITY);
#pragma unroll
        for (int i = 0; i < 16; ++i) {
            float4 v = x4[base + t + 256 * i];
            pm.x = fmaxf(pm.x, v.x); pm.y = fmaxf(pm.y, v.y);
            pm.z = fmaxf(pm.z, v.z); pm.w = fmaxf(pm.w, v.w);
        }
        // reduce the 4 c-slices inside this wave (lanes xor 16, 32)
#pragma unroll
        for (int off = 16; off <= 32; off <<= 1) {
            pm.x = fmaxf(pm.x, __shfl_xor(pm.x, off, 64));
            pm.y = fmaxf(pm.y, __shfl_xor(pm.y, off, 64));
            pm.z = fmaxf(pm.z, __shfl_xor(pm.z, off, 64));
            pm.w = fmaxf(pm.w, __shfl_xor(pm.w, off, 64));
        }
        const int wv = t >> 6, lane = t & 63;
        if (lane < 16) red[r][wv * 16 + lane] = pm;
    }
    __syncthreads();
    if (t < 16) {
#pragma unroll
        for (int r = 0; r < 2; ++r) {
            float4 a = red[r][t];
#pragma unroll
            for (int w = 1; w < 4; ++w) {
                float4 o = red[r][w * 16 + t];
                a.x = fmaxf(a.x, o.x); a.y = fmaxf(a.y, o.y);
                a.z = fmaxf(a.z, o.z); a.w = fmaxf(a.w, o.w);
            }
            float* dst = part + (size_t)(bid + r * nblk) * 64 + t * 4;
            dst[0] = a.x; dst[1] = a.y; dst[2] = a.z; dst[3] = a.w;
        }
    }
    grid.sync();

    // ---- Phase 2: middle network, one wave per batch, blocks 0..B-1 ----
    if (bid < B && t < 64) {
        const int b = bid;
        const float* pb = part + (size_t)b * 256;
        float m = fmaxf(fmaxf(pb[t], pb[64 + t]), fmaxf(pb[128 + t], pb[192 + t]));
        sm[t] = m;
        const float sgum = gumbel01((unsigned)(b * 64 + t));
        __builtin_amdgcn_wave_barrier();

        // windows: categorical (gumbel) + max + mean; 4-lane shfl argmax
        {
            int w = t >> 2, j = t & 3;
            int hh = 2 * (w >> 2) + (j >> 1), ww = 2 * (w & 3) + (j & 1);
            float v = sm[hh * 8 + ww];
            float wc = bad_val(v) ? EPSV : v;
            float s = wc + sgum;
            int bi = j;
            float bwc = wc;
            float mx = v;
            float ssum = v;
#pragma unroll
            for (int mk = 1; mk <= 2; mk <<= 1) {
                float s2   = __shfl_xor(s, mk, 64);
                int   bi2  = __shfl_xor(bi, mk, 64);
                float bwc2 = __shfl_xor(bwc, mk, 64);
                float mx2  = __shfl_xor(mx, mk, 64);
                float ss2  = __shfl_xor(ssum, mk, 64);
                bool take = (s2 > s) || (s2 == s && bi2 < bi);
                if (take) { s = s2; bi = bi2; bwc = bwc2; }
                mx = fmaxf(mx, mx2);
                ssum += ss2;
            }
            if (j == 0) sa16[w] = 0.1f * bwc + 0.6f * mx + 0.3f * (ssum * 0.25f);
        }
        __builtin_amdgcn_wave_barrier();

        // 3x3 conv (1->1, SAME, no bias) on 4x4, lanes 0..15
        if (t < 16) {
            int i = t >> 2, j = t & 3;
            float acc = 0.0f;
#pragma unroll
            for (int dy = -1; dy <= 1; ++dy) {
                int yy = i + dy;
                if (yy < 0 || yy > 3) continue;
#pragma unroll
                for (int dx = -1; dx <= 1; ++dx) {
                    int xx = j + dx;
                    if (xx < 0 || xx > 3) continue;
                    acc += sa16[yy * 4 + xx] * w11[(dy + 1) * 3 + (dx + 1)];
                }
            }
            sb16[t] = acc;
        }
        __builtin_amdgcn_wave_barrier();

        // bilinear 4x4 -> 8x8 (align_corners=False)
        {
            int y = t >> 3, xx2 = t & 7;
            float sy = (y + 0.5f) * 0.5f - 0.5f;
            float sx = (xx2 + 0.5f) * 0.5f - 0.5f;
            float fy = fminf(fmaxf(sy, 0.0f), 3.0f);
            float fx = fminf(fmaxf(sx, 0.0f), 3.0f);
            int iy0 = (int)floorf(fy); int iy1 = min(iy0 + 1, 3); float ry = fy - (float)iy0;
            int ix0 = (int)floorf(fx); int ix1 = min(ix0 + 1, 3); float rx = fx - (float)ix0;
            float v00 = sb16[iy0 * 4 + ix0], v01 = sb16[iy0 * 4 + ix1];
            float v10 = sb16[iy1 * 4 + ix0], v11 = sb16[iy1 * 4 + ix1];
            float top = v00 * (1.0f - rx) + v01 * rx;
            float bot = v10 * (1.0f - rx) + v11 * rx;
            so2[t] = top * (1.0f - ry) + bot * ry;
        }
        __builtin_amdgcn_wave_barrier();

        // conv5: [2->4] 3x3 SAME + bias + relu on 8x8
        {
            int y = t >> 3, x2 = t & 7;
            float a0 = b5[0], a1 = b5[1], a2 = b5[2], a3 = b5[3];
#pragma unroll
            for (int dy = -1; dy <= 1; ++dy) {
                int yy = y + dy;
                if (yy < 0 || yy > 7) continue;
#pragma unroll
                for (int dx = -1; dx <= 1; ++dx) {
                    int xx = x2 + dx;
                    if (xx < 0 || xx > 7) continue;
                    float i0 = sm[yy * 8 + xx];
                    float i1 = so2[yy * 8 + xx];
                    int kk = (dy + 1) * 3 + (dx + 1);
                    a0 += i0 * w5[0 * 18 + kk] + i1 * w5[0 * 18 + 9 + kk];
                    a1 += i0 * w5[1 * 18 + kk] + i1 * w5[1 * 18 + 9 + kk];
                    a2 += i0 * w5[2 * 18 + kk] + i1 * w5[2 * 18 + 9 + kk];
                    a3 += i0 * w5[3 * 18 + kk] + i1 * w5[3 * 18 + 9 + kk];
                }
            }
            shid[0 * 64 + t] = fmaxf(a0, 0.0f);
            shid[1 * 64 + t] = fmaxf(a1, 0.0f);
            shid[2 * 64 + t] = fmaxf(a2, 0.0f);
            shid[3 * 64 + t] = fmaxf(a3, 0.0f);
        }
        __builtin_amdgcn_wave_barrier();

        // conv6: [4->1] 3x3 SAME + bias + sigmoid -> gate
        {
            int y = t >> 3, x2 = t & 7;
            float acc = b6[0];
#pragma unroll
            for (int dy = -1; dy <= 1; ++dy) {
                int yy = y + dy;
                if (yy < 0 || yy > 7) continue;
#pragma unroll
                for (int dx = -1; dx <= 1; ++dx) {
                    int xx = x2 + dx;
                    if (xx < 0 || xx > 7) continue;
                    int kk = (dy + 1) * 3 + (dx + 1);
                    int p = yy * 8 + xx;
                    acc += shid[0 * 64 + p] * w6[0 + kk]
                         + shid[1 * 64 + p] * w6[9 + kk]
                         + shid[2 * 64 + p] * w6[18 + kk]
                         + shid[3 * 64 + p] * w6[27 + kk];
                }
            }
            gate[(size_t)b * 64 + t] = 1.0f / (1.0f + expf(-acc));
        }
    }
    grid.sync();

    // ---- Phase 3: out = relu(x * gate); x from L2/LLC, nt stores ----
#pragma unroll
    for (int r = 0; r < 2; ++r) {
        const int qb = bid + r * nblk;
        const int b = qb >> 2;
        const size_t base = (size_t)qb * 4096;
        const float4 gv = ((const float4*)(gate + (size_t)b * 64))[t & 15];
#pragma unroll
        for (int i = 0; i < 16; ++i) {
            size_t idx = base + t + 256 * i;
            float4 v = x4[idx];
            f32x4_t o;
            o.x = fmaxf(v.x * gv.x, 0.0f);
            o.y = fmaxf(v.y * gv.y, 0.0f);
            o.z = fmaxf(v.z * gv.z, 0.0f);
            o.w = fmaxf(v.w * gv.w, 0.0f);
            __builtin_nontemporal_store(o, (f32x4_t*)&o4[idx]);
        }
    }
}

extern "C" void kernel_launch(void* const* d_in, const int* in_sizes, int n_in,
                              void* d_out, int out_size, void* d_ws, size_t ws_size,
                              hipStream_t stream) {
    const float* x   = (const float*)d_in[0];
    const float* w11 = (const float*)d_in[1];
    const float* w5  = (const float*)d_in[2];
    const float* b5  = (const float*)d_in[3];
    const float* w6  = (const float*)d_in[4];
    const float* b6  = (const float*)d_in[5];
    float* out  = (float*)d_out;

    int B = in_sizes[0] / (C_DIM * HW);  // 512
    float* gate = (float*)d_ws;                    // B*64 floats   = 128 KB
    float* part = (float*)d_ws + (size_t)B * 64;   // B*4*64 floats = 512 KB

    int nblk = B * 2;  // 1024 blocks x 256 threads = 4 blocks/CU, co-resident
    void* args[] = { (void*)&x, (void*)&w11, (void*)&w5, (void*)&b5,
                     (void*)&w6, (void*)&b6, (void*)&out,
                     (void*)&part, (void*)&gate, (void*)&B };
    hipLaunchCooperativeKernel((const void*)sa_coop_kernel,
                               dim3(nblk), dim3(256), args, 0, stream);
}

// Round 8
// 250.585 us; speedup vs baseline: 1.8815x; 1.8815x over previous
//
#include <hip/hip_runtime.h>
#include <math.h>

// x [B=512, C=1024, H=8, W=8] f32. out same shape.
#define C_DIM 1024
#define HW 64
#define NT 512              // threads per block, 8 waves
#define F4B 16384           // C_DIM*HW/4 float4 per batch
#define PER_T 32            // F4B / NT float4 per thread
#define EPSV 1e-8f
#define TINYF 1.17549435e-38f

typedef float f32x4_t __attribute__((ext_vector_type(4)));

__device__ __forceinline__ void threefry2x32_01(unsigned x0, unsigned x1,
                                                unsigned& o0, unsigned& o1) {
    const unsigned ks0 = 0u, ks1 = 1u, ks2 = 0x1BD11BDBu; // 0x1BD11BDA ^ 0 ^ 1
    x0 += ks0; x1 += ks1;
#define TF_R(r) { x0 += x1; x1 = (x1 << (r)) | (x1 >> (32 - (r))); x1 ^= x0; }
    TF_R(13) TF_R(15) TF_R(26) TF_R(6)
    x0 += ks1; x1 += ks2 + 1u;
    TF_R(17) TF_R(29) TF_R(16) TF_R(24)
    x0 += ks2; x1 += ks0 + 2u;
    TF_R(13) TF_R(15) TF_R(26) TF_R(6)
    x0 += ks0; x1 += ks1 + 3u;
    TF_R(17) TF_R(29) TF_R(16) TF_R(24)
    x0 += ks1; x1 += ks2 + 4u;
    TF_R(13) TF_R(15) TF_R(26) TF_R(6)
    x0 += ks2; x1 += ks0 + 5u;
#undef TF_R
    o0 = x0; o1 = x1;
}

// jax_threefry_partitionable=True: counter (hi=0, lo=n), out = o0 ^ o1.
__device__ __forceinline__ unsigned jax_random_bits(unsigned n) {
    unsigned o0, o1;
    threefry2x32_01(0u, n, o0, o1);
    return o0 ^ o1;
}

__device__ __forceinline__ float gumbel01(unsigned n) {
    unsigned bits = jax_random_bits(n);
    float f = __uint_as_float(0x3F800000u | (bits >> 9)) - 1.0f;
    float u = fmaxf(TINYF, f + TINYF);
    return -logf(-logf(u));
}

__device__ __forceinline__ bool bad_val(float v) {
    return ((__float_as_uint(v) & 0x7F800000u) == 0x7F800000u) || (v < 0.0f);
}

// ---------------- Fused kernel, 512-thread blocks, 2 blocks/CU --------------
// One block per batch; 512 blocks = exactly one full-GPU residency round.
// __launch_bounds__(512,4): 4 waves/EU -> VGPR cap 128 (vs 64 at 1024 thr)
// -> deep load pipeline. 2 blocks/CU run out of phase, so one block's wave-0
// middle (~2.5us) hides under the other block's streaming. No register pin:
// apply re-reads x from LLC (r1-vs-r4 proved this perf-equal to reg cache).
__global__ __launch_bounds__(NT, 4) void sa_fused_kernel(
    const float* __restrict__ x,
    const float* __restrict__ w11,
    const float* __restrict__ w5,
    const float* __restrict__ b5,
    const float* __restrict__ w6,
    const float* __restrict__ b6,
    float* __restrict__ out)
{
    const int b = blockIdx.x;
    const int t = threadIdx.x;

    const float4* __restrict__ xb = (const float4*)x + (size_t)b * F4B;
    float4* __restrict__ ob = (float4*)out + (size_t)b * F4B;

    __shared__ float4 red[8 * 16];        // 8 wave partials x 16 hw4 groups
    __shared__ float sm[64], sa16[16], sb16[16], so2[64], shid[4 * 64];
    __shared__ __align__(16) float sgate[64];

    // ---- Phase 1: streaming channel max. Thread t covers f4 idx t + 512*i
    //      -> hw4 group t&15 fixed. Rolling reduce, compiler-depth pipeline.
    float4 pm = make_float4(-INFINITY, -INFINITY, -INFINITY, -INFINITY);
#pragma unroll
    for (int i = 0; i < PER_T; ++i) {
        float4 v = xb[t + NT * i];
        pm.x = fmaxf(pm.x, v.x); pm.y = fmaxf(pm.y, v.y);
        pm.z = fmaxf(pm.z, v.z); pm.w = fmaxf(pm.w, v.w);
    }
    // reduce the 4 c-slices within this wave (lanes xor 16, 32)
#pragma unroll
    for (int off = 16; off <= 32; off <<= 1) {
        pm.x = fmaxf(pm.x, __shfl_xor(pm.x, off, 64));
        pm.y = fmaxf(pm.y, __shfl_xor(pm.y, off, 64));
        pm.z = fmaxf(pm.z, __shfl_xor(pm.z, off, 64));
        pm.w = fmaxf(pm.w, __shfl_xor(pm.w, off, 64));
    }
    const int wv = t >> 6, lane = t & 63;
    if (lane < 16) red[wv * 16 + lane] = pm;
    __syncthreads();

    // ---- Phase 2: middle network, wave 0 only (barrier-free inside) ----
    if (t < 64) {
        // reduce 8 wave partials: 2 per lane + xor16/32 shuffles
        {
            int g = t & 15, set = t >> 4;  // set = 0..3
            float4 a = red[(set * 2 + 0) * 16 + g];
            float4 o = red[(set * 2 + 1) * 16 + g];
            a.x = fmaxf(a.x, o.x); a.y = fmaxf(a.y, o.y);
            a.z = fmaxf(a.z, o.z); a.w = fmaxf(a.w, o.w);
#pragma unroll
            for (int off = 16; off <= 32; off <<= 1) {
                a.x = fmaxf(a.x, __shfl_xor(a.x, off, 64));
                a.y = fmaxf(a.y, __shfl_xor(a.y, off, 64));
                a.z = fmaxf(a.z, __shfl_xor(a.z, off, 64));
                a.w = fmaxf(a.w, __shfl_xor(a.w, off, 64));
            }
            if (t < 16) {
                sm[t * 4 + 0] = a.x; sm[t * 4 + 1] = a.y;
                sm[t * 4 + 2] = a.z; sm[t * 4 + 3] = a.w;
            }
        }
        const float sgum = gumbel01((unsigned)(b * 64 + t));
        __builtin_amdgcn_wave_barrier();

        // windows: categorical (gumbel) + max + mean; 4-lane shfl argmax,
        // first-max tie-break = JAX semantics
        {
            int w = t >> 2, j = t & 3;
            int hh = 2 * (w >> 2) + (j >> 1), ww = 2 * (w & 3) + (j & 1);
            float v = sm[hh * 8 + ww];
            float wc = bad_val(v) ? EPSV : v;
            float s = wc + sgum;
            int bi = j;
            float bwc = wc;
            float mx = v;
            float ssum = v;
#pragma unroll
            for (int mk = 1; mk <= 2; mk <<= 1) {
                float s2   = __shfl_xor(s, mk, 64);
                int   bi2  = __shfl_xor(bi, mk, 64);
                float bwc2 = __shfl_xor(bwc, mk, 64);
                float mx2  = __shfl_xor(mx, mk, 64);
                float ss2  = __shfl_xor(ssum, mk, 64);
                bool take = (s2 > s) || (s2 == s && bi2 < bi);
                if (take) { s = s2; bi = bi2; bwc = bwc2; }
                mx = fmaxf(mx, mx2);
                ssum += ss2;
            }
            if (j == 0) sa16[w] = 0.1f * bwc + 0.6f * mx + 0.3f * (ssum * 0.25f);
        }
        __builtin_amdgcn_wave_barrier();

        // 3x3 conv (1->1, SAME, no bias) on 4x4, lanes 0..15
        if (t < 16) {
            int i = t >> 2, j = t & 3;
            float acc = 0.0f;
#pragma unroll
            for (int dy = -1; dy <= 1; ++dy) {
                int yy = i + dy;
                if (yy < 0 || yy > 3) continue;
#pragma unroll
                for (int dx = -1; dx <= 1; ++dx) {
                    int xx = j + dx;
                    if (xx < 0 || xx > 3) continue;
                    acc += sa16[yy * 4 + xx] * w11[(dy + 1) * 3 + (dx + 1)];
                }
            }
            sb16[t] = acc;
        }
        __builtin_amdgcn_wave_barrier();

        // bilinear 4x4 -> 8x8 (align_corners=False)
        {
            int y = t >> 3, xx2 = t & 7;
            float sy = (y + 0.5f) * 0.5f - 0.5f;
            float sx = (xx2 + 0.5f) * 0.5f - 0.5f;
            float fy = fminf(fmaxf(sy, 0.0f), 3.0f);
            float fx = fminf(fmaxf(sx, 0.0f), 3.0f);
            int iy0 = (int)floorf(fy); int iy1 = min(iy0 + 1, 3); float ry = fy - (float)iy0;
            int ix0 = (int)floorf(fx); int ix1 = min(ix0 + 1, 3); float rx = fx - (float)ix0;
            float v00 = sb16[iy0 * 4 + ix0], v01 = sb16[iy0 * 4 + ix1];
            float v10 = sb16[iy1 * 4 + ix0], v11 = sb16[iy1 * 4 + ix1];
            float top = v00 * (1.0f - rx) + v01 * rx;
            float bot = v10 * (1.0f - rx) + v11 * rx;
            so2[t] = top * (1.0f - ry) + bot * ry;
        }
        __builtin_amdgcn_wave_barrier();

        // conv5: [2->4] 3x3 SAME + bias + relu on 8x8 (ch0 = m, ch1 = out2)
        {
            int y = t >> 3, x2 = t & 7;
            float a0 = b5[0], a1 = b5[1], a2 = b5[2], a3 = b5[3];
#pragma unroll
            for (int dy = -1; dy <= 1; ++dy) {
                int yy = y + dy;
                if (yy < 0 || yy > 7) continue;
#pragma unroll
                for (int dx = -1; dx <= 1; ++dx) {
                    int xx = x2 + dx;
                    if (xx < 0 || xx > 7) continue;
                    float i0 = sm[yy * 8 + xx];
                    float i1 = so2[yy * 8 + xx];
                    int kk = (dy + 1) * 3 + (dx + 1);
                    a0 += i0 * w5[0 * 18 + kk] + i1 * w5[0 * 18 + 9 + kk];
                    a1 += i0 * w5[1 * 18 + kk] + i1 * w5[1 * 18 + 9 + kk];
                    a2 += i0 * w5[2 * 18 + kk] + i1 * w5[2 * 18 + 9 + kk];
                    a3 += i0 * w5[3 * 18 + kk] + i1 * w5[3 * 18 + 9 + kk];
                }
            }
            shid[0 * 64 + t] = fmaxf(a0, 0.0f);
            shid[1 * 64 + t] = fmaxf(a1, 0.0f);
            shid[2 * 64 + t] = fmaxf(a2, 0.0f);
            shid[3 * 64 + t] = fmaxf(a3, 0.0f);
        }
        __builtin_amdgcn_wave_barrier();

        // conv6: [4->1] 3x3 SAME + bias + sigmoid -> gate (LDS)
        {
            int y = t >> 3, x2 = t & 7;
            float acc = b6[0];
#pragma unroll
            for (int dy = -1; dy <= 1; ++dy) {
                int yy = y + dy;
                if (yy < 0 || yy > 7) continue;
#pragma unroll
                for (int dx = -1; dx <= 1; ++dx) {
                    int xx = x2 + dx;
                    if (xx < 0 || xx > 7) continue;
                    int kk = (dy + 1) * 3 + (dx + 1);
                    int p = yy * 8 + xx;
                    acc += shid[0 * 64 + p] * w6[0 + kk]
                         + shid[1 * 64 + p] * w6[9 + kk]
                         + shid[2 * 64 + p] * w6[18 + kk]
                         + shid[3 * 64 + p] * w6[27 + kk];
                }
            }
            sgate[t] = 1.0f / (1.0f + expf(-acc));
        }
    }
    __syncthreads();

    // ---- Phase 3: out = relu(x * gate); x re-read from LLC; nt stores ----
    const float4 gv = ((const float4*)sgate)[t & 15];
#pragma unroll
    for (int i = 0; i < PER_T; ++i) {
        float4 v = xb[t + NT * i];
        f32x4_t o;
        o.x = fmaxf(v.x * gv.x, 0.0f);
        o.y = fmaxf(v.y * gv.y, 0.0f);
        o.z = fmaxf(v.z * gv.z, 0.0f);
        o.w = fmaxf(v.w * gv.w, 0.0f);
        __builtin_nontemporal_store(o, (f32x4_t*)&ob[t + NT * i]);
    }
}

extern "C" void kernel_launch(void* const* d_in, const int* in_sizes, int n_in,
                              void* d_out, int out_size, void* d_ws, size_t ws_size,
                              hipStream_t stream) {
    const float* x   = (const float*)d_in[0];
    const float* w11 = (const float*)d_in[1];
    const float* w5  = (const float*)d_in[2];
    const float* b5  = (const float*)d_in[3];
    const float* w6  = (const float*)d_in[4];
    const float* b6  = (const float*)d_in[5];
    float* out  = (float*)d_out;

    int B = in_sizes[0] / (C_DIM * HW);  // 512
    sa_fused_kernel<<<dim3(B), dim3(NT), 0, stream>>>(x, w11, w5, b5, w6, b6, out);
}